// Round 2
// baseline (160.037 us; speedup 1.0000x reference)
//
#include <hip/hip_runtime.h>

#define NPTS 65536
#define NB 32
#define H 256

typedef __attribute__((ext_vector_type(8))) short bhalf8;   // 8 bf16 in 4 VGPRs
typedef __attribute__((ext_vector_type(4))) float f32x4;

__device__ __forceinline__ float bf2f(ushort u) {
  union { unsigned u; float f; } x; x.u = ((unsigned)u) << 16; return x.f;
}
__device__ __forceinline__ ushort f2bf(float f) {
  union { float f; unsigned u; } x; x.f = f;
  unsigned r = x.u + 0x7FFFu + ((x.u >> 16) & 1u);
  return (ushort)(r >> 16);
}

// ---- runtime dtype detection from W1's bit pattern (wave-uniform) ----
// bf16 array: even halfwords are Glorot weights, exponent field in [0x70,0x7E].
// f32 array:  even halfwords are low mantissa bits -> uniform exponent field.
__device__ __forceinline__ bool detect_bf16(const void* W1) {
  const ushort* u = (const ushort*)W1;
  int cnt = 0;
#pragma unroll
  for (int k = 0; k < 64; k++) {
    int e = (u[2 * k] >> 7) & 0xFF;
    cnt += (e >= 0x70 && e <= 0x7E) ? 1 : 0;
  }
  return cnt >= 32;
}

template<bool B16> __device__ __forceinline__ float LD(const void* p, int i) {
  if constexpr (B16) return bf2f(((const ushort*)p)[i]);
  else               return ((const float*)p)[i];
}
template<bool B16> __device__ __forceinline__ void ST(void* p, int i, float v) {
  if constexpr (B16) ((ushort*)p)[i] = f2bf(v);
  else               ((float*)p)[i] = v;
}

// Pre-swizzle W1 [256][256] and W2 [256][32] (row-major, k-major) into MFMA
// B-fragment order (always bf16 out): frag(ct,kk) = 64 lanes x 16B; lane l holds
// B[kk*32 + (l>>4)*8 + j][ct*16 + (l&15)], j=0..7.
template<bool B16>
__device__ void swz_body(const void* W1, const void* W2,
                         ushort* __restrict__ W1s, ushort* __restrict__ W2s, int tid) {
  if (tid < 8192) {                       // 16 ct * 8 kk * 64 lanes
    int lane = tid & 63, kk = (tid >> 6) & 7, ct = tid >> 9;
    int q = lane >> 4, r = lane & 15;
    int kb = kk * 32 + q * 8, n = ct * 16 + r;
    bhalf8 v;
#pragma unroll
    for (int j = 0; j < 8; j++) v[j] = (short)f2bf(LD<B16>(W1, (kb + j) * H + n));
    *(bhalf8*)(W1s + tid * 8) = v;
  } else if (tid < 8192 + 1024) {         // 2 ct * 8 kk * 64 lanes
    int t2 = tid - 8192;
    int lane = t2 & 63, kk = (t2 >> 6) & 7, ct = t2 >> 9;
    int q = lane >> 4, r = lane & 15;
    int kb = kk * 32 + q * 8, n = ct * 16 + r;
    bhalf8 v;
#pragma unroll
    for (int j = 0; j < 8; j++) v[j] = (short)f2bf(LD<B16>(W2, (kb + j) * NB + n));
    *(bhalf8*)(W2s + t2 * 8) = v;
  }
}

__global__ void swz_kernel(const void* W1, const void* W2,
                           ushort* __restrict__ W1s, ushort* __restrict__ W2s) {
  int tid = blockIdx.x * 256 + threadIdx.x;
  if (detect_bf16(W1)) swz_body<true>(W1, W2, W1s, W2s, tid);
  else                 swz_body<false>(W1, W2, W1s, W2s, tid);
}

#define APITCH 264   // bf16 elems/row: 528B -> dword pitch 132, conflict-free b128

struct Smem {
  alignas(16) ushort Abuf[48 * APITCH];   // A for GEMM1, then h1 for GEMM2
  alignas(16) float outb[48 * 33];        // out / out_t / out_tt (f32)
  alignas(16) float lambS[32 * 34];       // lambda_b padded
  alignas(16) float sinb[16 * 33];
  alignas(16) float cosb[16 * 33];
};

template<bool B16>
__device__ void pinn_body(Smem& sm,
                          const void* timeP, const void* powerP,
                          const void* W0, const void* b0,
                          const void* b1, const void* b2,
                          const void* lam_m, const void* lam_d,
                          const void* lam_b, const void* bwi,
                          const ushort* __restrict__ W1s, const ushort* __restrict__ W2s,
                          void* outP) {
  const int tid = threadIdx.x;
  const int s0 = blockIdx.x * 16;

  // ---- preload lambda_b into LDS (padded) ----
  for (int idx = tid; idx < NB * NB; idx += 256)
    sm.lambS[(idx >> 5) * 34 + (idx & 31)] = LD<B16>(lam_b, idx);

  // ---- Phase 1: A = [h0 ; h0' ; h0''] for 16 samples ----
  {
    int sl = tid & 15;          // sample within tile
    int g = tid >> 4;           // k-group
    float t = LD<B16>(timeP, s0 + sl);
    float x = t * 0.1f - 1.0f;  // 2t/TMAX - 1, TMAX=20
    int k0 = g * 16;
#pragma unroll 4
    for (int kc = 0; kc < 16; kc++) {
      int k = k0 + kc;
      float w0 = LD<B16>(W0, k);
      float pre = x * w0 + LD<B16>(b0, k);
      float v = tanhf(pre);
      float c = w0 * 0.1f;                 // dpre/dt
      float s2 = 1.0f - v * v;
      float d1 = s2 * c;
      float d2 = -2.0f * v * d1 * c;
      sm.Abuf[sl * APITCH + k]        = f2bf(v);
      sm.Abuf[(16 + sl) * APITCH + k] = f2bf(d1);
      sm.Abuf[(32 + sl) * APITCH + k] = f2bf(d2);
    }
  }
  __syncthreads();

  const int wave = tid >> 6, lane = tid & 63;
  const int q = lane >> 4, r = lane & 15;

  // ---- Phase 2: GEMM1  z1[48][256] = A[48][256] @ W1[256][256] ----
  f32x4 acc[3][4];
#pragma unroll
  for (int rt = 0; rt < 3; rt++)
#pragma unroll
    for (int ci = 0; ci < 4; ci++) { f32x4 z = {0.f, 0.f, 0.f, 0.f}; acc[rt][ci] = z; }

#pragma unroll
  for (int kk = 0; kk < 8; kk++) {
    bhalf8 a0 = *(const bhalf8*)(sm.Abuf + (0 * 16 + r) * APITCH + kk * 32 + q * 8);
    bhalf8 a1 = *(const bhalf8*)(sm.Abuf + (1 * 16 + r) * APITCH + kk * 32 + q * 8);
    bhalf8 a2 = *(const bhalf8*)(sm.Abuf + (2 * 16 + r) * APITCH + kk * 32 + q * 8);
#pragma unroll
    for (int ci = 0; ci < 4; ci++) {
      int ct = wave * 4 + ci;
      bhalf8 bfr = *(const bhalf8*)(W1s + ((ct * 8 + kk) * 64 + lane) * 8);
      acc[0][ci] = __builtin_amdgcn_mfma_f32_16x16x32_bf16(a0, bfr, acc[0][ci], 0, 0, 0);
      acc[1][ci] = __builtin_amdgcn_mfma_f32_16x16x32_bf16(a1, bfr, acc[1][ci], 0, 0, 0);
      acc[2][ci] = __builtin_amdgcn_mfma_f32_16x16x32_bf16(a2, bfr, acc[2][ci], 0, 0, 0);
    }
  }
  __syncthreads();   // all waves done READING Abuf before overwrite with h1

  // ---- Phase 3: bias + tanh chain on C-layout tiles (col=lane&15, row=q*4+i) ----
#pragma unroll
  for (int ci = 0; ci < 4; ci++) {
    int ct = wave * 4 + ci;
    int col = ct * 16 + r;
    float b1v = LD<B16>(b1, col);
#pragma unroll
    for (int i = 0; i < 4; i++) {
      float zv  = acc[0][ci][i] + b1v;   // bias only on value channel
      float zd  = acc[1][ci][i];
      float zdd = acc[2][ci][i];
      float hv  = tanhf(zv);
      float s2  = 1.0f - hv * hv;
      float hd  = s2 * zd;
      float hdd = s2 * zdd - 2.0f * hv * hd * zd;
      int s = q * 4 + i;
      sm.Abuf[s * APITCH + col]        = f2bf(hv);
      sm.Abuf[(16 + s) * APITCH + col] = f2bf(hd);
      sm.Abuf[(32 + s) * APITCH + col] = f2bf(hdd);
    }
  }
  __syncthreads();

  // ---- Phase 4: GEMM2  out[48][32] = h1[48][256] @ W2[256][32] ----
  for (int tI = wave; tI < 6; tI += 4) {
    int rt = tI >> 1, ct2 = tI & 1;
    f32x4 acc2 = {0.f, 0.f, 0.f, 0.f};
#pragma unroll
    for (int kk = 0; kk < 8; kk++) {
      bhalf8 a = *(const bhalf8*)(sm.Abuf + (rt * 16 + r) * APITCH + kk * 32 + q * 8);
      bhalf8 b = *(const bhalf8*)(W2s + ((ct2 * 8 + kk) * 64 + lane) * 8);
      acc2 = __builtin_amdgcn_mfma_f32_16x16x32_bf16(a, b, acc2, 0, 0, 0);
    }
    int col = ct2 * 16 + r;
    float badd = (rt == 0) ? LD<B16>(b2, col) : 0.0f;
#pragma unroll
    for (int i = 0; i < 4; i++)
      sm.outb[(rt * 16 + q * 4 + i) * 33 + col] = acc2[i] + badd;
  }
  __syncthreads();

  // ---- Phase 5a: sin/cos of angles ----
  for (int slot = tid; slot < 512; slot += 256) {
    int s = slot >> 5, b = slot & 31;
    float dv = sm.outb[s * 33 + b];
    sm.sinb[s * 33 + b] = sinf(dv);
    sm.cosb[s * 33 + b] = cosf(dv);
  }
  __syncthreads();

  // ---- Phase 5b: coupling + physics + stores ----
  // sum_j B[b][j] sin(dv_b - dv_j) = sin(dv_b)*S_c - cos(dv_b)*S_s
  for (int slot = tid; slot < 512; slot += 256) {
    int s = slot >> 5, b = slot & 31;
    float dv  = sm.outb[s * 33 + b];
    float dt  = sm.outb[(16 + s) * 33 + b];
    float dtt = sm.outb[(32 + s) * 33 + b];
    float accC = 0.f, accS = 0.f;
#pragma unroll 8
    for (int j = 0; j < 32; j++) {
      float lb = sm.lambS[b * 34 + j];
      accC += lb * sm.cosb[s * 33 + j];
      accS += lb * sm.sinb[s * 33 + j];
    }
    float conn = sm.sinb[s * 33 + b] * accC - sm.cosb[s * 33 + b] * accS;
    int n = s0 + s;
    float phys = LD<B16>(lam_m, b) * LD<B16>(bwi, b) * dtt + LD<B16>(lam_d, b) * dt
               + conn - LD<B16>(powerP, n * 32 + b);
    ST<B16>(outP, n * 32 + b, dv);
    ST<B16>(outP, NPTS * 32 + n * 32 + b, dt);
    ST<B16>(outP, 2 * NPTS * 32 + n * 32 + b, phys);
  }
}

__global__ __launch_bounds__(256, 2)
void pinn_kernel(const void* timeP, const void* powerP,
                 const void* W0, const void* b0,
                 const void* b1, const void* b2,
                 const void* lam_m, const void* lam_d,
                 const void* lam_b, const void* bwi,
                 const void* W1_for_detect,
                 const ushort* __restrict__ W1s, const ushort* __restrict__ W2s,
                 void* outP) {
  __shared__ Smem sm;
  if (detect_bf16(W1_for_detect))
    pinn_body<true>(sm, timeP, powerP, W0, b0, b1, b2, lam_m, lam_d, lam_b, bwi,
                    W1s, W2s, outP);
  else
    pinn_body<false>(sm, timeP, powerP, W0, b0, b1, b2, lam_m, lam_d, lam_b, bwi,
                     W1s, W2s, outP);
}

extern "C" void kernel_launch(void* const* d_in, const int* in_sizes, int n_in,
                              void* d_out, int out_size, void* d_ws, size_t ws_size,
                              hipStream_t stream) {
  const void* timeP  = d_in[0];
  const void* powerP = d_in[1];
  const void* W0     = d_in[2];
  const void* b0     = d_in[3];
  const void* W1     = d_in[4];
  const void* b1     = d_in[5];
  const void* W2     = d_in[6];
  const void* b2     = d_in[7];
  const void* lam_m  = d_in[8];
  const void* lam_d  = d_in[9];
  const void* lam_b  = d_in[10];
  const void* bwi    = d_in[11];

  ushort* W1s = (ushort*)d_ws;            // 65536 elems = 128 KB
  ushort* W2s = W1s + H * H;              // 8192 elems  = 16 KB

  swz_kernel<<<36, 256, 0, stream>>>(W1, W2, W1s, W2s);
  pinn_kernel<<<NPTS / 16, 256, 0, stream>>>(timeP, powerP, W0, b0, b1, b2,
                                             lam_m, lam_d, lam_b, bwi, W1,
                                             W1s, W2s, d_out);
}

// Round 3
// 159.671 us; speedup vs baseline: 1.0023x; 1.0023x over previous
//
#include <hip/hip_runtime.h>

#define NPTS 65536
#define NB 32
#define H 256

typedef __attribute__((ext_vector_type(8))) short bhalf8;   // 8 bf16 in 4 VGPRs
typedef __attribute__((ext_vector_type(4))) float f32x4;

__device__ __forceinline__ float bf2f(ushort u) {
  union { unsigned u; float f; } x; x.u = ((unsigned)u) << 16; return x.f;
}
__device__ __forceinline__ ushort f2bf(float f) {
  union { float f; unsigned u; } x; x.f = f;
  unsigned r = x.u + 0x7FFFu + ((x.u >> 16) & 1u);
  return (ushort)(r >> 16);
}
// tanh(z) = 1 - 2/(e^{2z}+1): v_mul + v_exp + v_add + v_rcp + v_fma (~6 ops vs ~40 for ocml tanhf)
__device__ __forceinline__ float fast_tanh(float z) {
  float e = __expf(2.0f * z);
  return 1.0f - 2.0f / (e + 1.0f);
}

// ---- runtime dtype detection from W1's bit pattern (wave-uniform, scalarizes) ----
__device__ __forceinline__ bool detect_bf16(const void* W1) {
  const ushort* u = (const ushort*)W1;
  int cnt = 0;
#pragma unroll
  for (int k = 0; k < 64; k++) {
    int e = (u[2 * k] >> 7) & 0xFF;
    cnt += (e >= 0x70 && e <= 0x7E) ? 1 : 0;
  }
  return cnt >= 32;
}

template<bool B16> __device__ __forceinline__ float LD(const void* p, int i) {
  if constexpr (B16) return bf2f(((const ushort*)p)[i]);
  else               return ((const float*)p)[i];
}
template<bool B16> __device__ __forceinline__ void ST(void* p, int i, float v) {
  if constexpr (B16) ((ushort*)p)[i] = f2bf(v);
  else               ((float*)p)[i] = v;
}
// 8 consecutive f32 values starting at element i8*8 (16B-aligned either dtype)
template<bool B16> __device__ __forceinline__ void LD8(const void* p, int i8, float* o) {
  if constexpr (B16) {
    bhalf8 x = *((const bhalf8*)p + i8);
#pragma unroll
    for (int j = 0; j < 8; j++) o[j] = bf2f((ushort)x[j]);
  } else {
    const float4* f = (const float4*)p;
    float4 a = f[i8 * 2], b = f[i8 * 2 + 1];
    o[0] = a.x; o[1] = a.y; o[2] = a.z; o[3] = a.w;
    o[4] = b.x; o[5] = b.y; o[6] = b.z; o[7] = b.w;
  }
}

// Pre-swizzle W1 [256][256], W2 [256][32] into MFMA B-frag order (bf16):
// frag(ct,kk): lane l=q*16+r holds B[kk*32+q*8+j][ct*16+r], j=0..7.
// One output element per thread; r in low bits -> coalesced source loads.
__global__ void swz_kernel(const void* W1, const void* W2,
                           ushort* __restrict__ W1s, ushort* __restrict__ W2s) {
  int gid = blockIdx.x * 256 + threadIdx.x;
  bool b16 = detect_bf16(W1);
  if (gid < 65536) {
    int r = gid & 15, q = (gid >> 4) & 3, j = (gid >> 6) & 7;
    int kk = (gid >> 9) & 7, ct = gid >> 12;
    int src = (kk * 32 + q * 8 + j) * H + ct * 16 + r;
    int dst = ((ct * 8 + kk) * 64 + q * 16 + r) * 8 + j;
    float v = b16 ? bf2f(((const ushort*)W1)[src]) : ((const float*)W1)[src];
    W1s[dst] = f2bf(v);
  } else {
    int g2 = gid - 65536;                 // [0, 8192)
    int r = g2 & 15, q = (g2 >> 4) & 3, j = (g2 >> 6) & 7;
    int kk = (g2 >> 9) & 7, ct = (g2 >> 12) & 1;
    int src = (kk * 32 + q * 8 + j) * NB + ct * 16 + r;
    int dst = ((ct * 8 + kk) * 64 + q * 16 + r) * 8 + j;
    float v = b16 ? bf2f(((const ushort*)W2)[src]) : ((const float*)W2)[src];
    W2s[dst] = f2bf(v);
  }
}

#define APITCH 264   // 528B rows = 33*16B: b128-aligned, dword pitch 132

struct Smem {
  alignas(16) ushort Abuf[48 * APITCH];   // A for GEMM1, then h1 for GEMM2
  alignas(16) float outb[48 * 33];        // out / out_t / out_tt (f32)
  alignas(16) float lambS[32 * 34];       // lambda_b padded
  alignas(16) float sinb[16 * 33];
  alignas(16) float cosb[16 * 33];
};

template<bool B16>
__device__ void pinn_body(Smem& sm,
                          const void* timeP, const void* powerP,
                          const void* W0, const void* b0,
                          const void* b1, const void* b2,
                          const void* lam_m, const void* lam_d,
                          const void* lam_b, const void* bwi,
                          const ushort* __restrict__ W1s, const ushort* __restrict__ W2s,
                          void* outP) {
  const int tid = threadIdx.x;
  const int s0 = blockIdx.x * 16;

  // ---- preload lambda_b into LDS (padded) ----
  for (int idx = tid; idx < NB * NB; idx += 256)
    sm.lambS[(idx >> 5) * 34 + (idx & 31)] = LD<B16>(lam_b, idx);

  // ---- Phase 1: A = [h0 ; h0' ; h0''], thread owns 16 consecutive k of 1 sample ----
  {
    int sl = tid >> 4;          // sample 0..15 (16 threads per sample)
    int kt = tid & 15;          // k-block: k = kt*16 .. kt*16+15
    float t = LD<B16>(timeP, s0 + sl);
    float x = t * 0.1f - 1.0f;  // 2t/TMAX - 1, TMAX=20
#pragma unroll
    for (int half = 0; half < 2; half++) {
      float w0v[8], b0v[8];
      LD8<B16>(W0, kt * 2 + half, w0v);
      LD8<B16>(b0, kt * 2 + half, b0v);
      bhalf8 hv, hd, hdd;
#pragma unroll
      for (int c = 0; c < 8; c++) {
        float pre = x * w0v[c] + b0v[c];
        float v = fast_tanh(pre);
        float cc = w0v[c] * 0.1f;            // dpre/dt
        float s2 = 1.0f - v * v;
        float d1 = s2 * cc;
        float d2 = -2.0f * v * d1 * cc;
        hv[c]  = (short)f2bf(v);
        hd[c]  = (short)f2bf(d1);
        hdd[c] = (short)f2bf(d2);
      }
      int off = sl * APITCH + kt * 16 + half * 8;
      *(bhalf8*)(sm.Abuf + off)               = hv;    // 3x ds_write_b128
      *(bhalf8*)(sm.Abuf + 16 * APITCH + off) = hd;
      *(bhalf8*)(sm.Abuf + 32 * APITCH + off) = hdd;
    }
  }
  __syncthreads();

  const int wave = tid >> 6, lane = tid & 63;
  const int q = lane >> 4, r = lane & 15;

  // ---- Phase 2: GEMM1  z1[48][256] = A[48][256] @ W1[256][256] ----
  f32x4 acc[3][4];
#pragma unroll
  for (int rt = 0; rt < 3; rt++)
#pragma unroll
    for (int ci = 0; ci < 4; ci++) { f32x4 z = {0.f, 0.f, 0.f, 0.f}; acc[rt][ci] = z; }

#pragma unroll
  for (int kk = 0; kk < 8; kk++) {
    bhalf8 a0 = *(const bhalf8*)(sm.Abuf + (0 * 16 + r) * APITCH + kk * 32 + q * 8);
    bhalf8 a1 = *(const bhalf8*)(sm.Abuf + (1 * 16 + r) * APITCH + kk * 32 + q * 8);
    bhalf8 a2 = *(const bhalf8*)(sm.Abuf + (2 * 16 + r) * APITCH + kk * 32 + q * 8);
#pragma unroll
    for (int ci = 0; ci < 4; ci++) {
      int ct = wave * 4 + ci;
      bhalf8 bfr = *(const bhalf8*)(W1s + ((ct * 8 + kk) * 64 + lane) * 8);
      acc[0][ci] = __builtin_amdgcn_mfma_f32_16x16x32_bf16(a0, bfr, acc[0][ci], 0, 0, 0);
      acc[1][ci] = __builtin_amdgcn_mfma_f32_16x16x32_bf16(a1, bfr, acc[1][ci], 0, 0, 0);
      acc[2][ci] = __builtin_amdgcn_mfma_f32_16x16x32_bf16(a2, bfr, acc[2][ci], 0, 0, 0);
    }
  }
  __syncthreads();   // all waves done READING Abuf before overwrite with h1

  // ---- Phase 3: bias + tanh chain on C-layout tiles (col=lane&15, row=q*4+i) ----
#pragma unroll
  for (int ci = 0; ci < 4; ci++) {
    int ct = wave * 4 + ci;
    int col = ct * 16 + r;
    float b1v = LD<B16>(b1, col);
#pragma unroll
    for (int i = 0; i < 4; i++) {
      float zv  = acc[0][ci][i] + b1v;   // bias only on value channel
      float zd  = acc[1][ci][i];
      float zdd = acc[2][ci][i];
      float hv  = fast_tanh(zv);
      float s2  = 1.0f - hv * hv;
      float hd  = s2 * zd;
      float hdd = s2 * zdd - 2.0f * hv * hd * zd;
      int s = q * 4 + i;
      sm.Abuf[s * APITCH + col]        = f2bf(hv);
      sm.Abuf[(16 + s) * APITCH + col] = f2bf(hd);
      sm.Abuf[(32 + s) * APITCH + col] = f2bf(hdd);
    }
  }
  __syncthreads();

  // ---- Phase 4: GEMM2 out[48][32] = h1[48][256] @ W2[256][32], sin/cos fused on rt=0 ----
  for (int tI = wave; tI < 6; tI += 4) {
    int rt = tI >> 1, ct2 = tI & 1;
    f32x4 acc2 = {0.f, 0.f, 0.f, 0.f};
#pragma unroll
    for (int kk = 0; kk < 8; kk++) {
      bhalf8 a = *(const bhalf8*)(sm.Abuf + (rt * 16 + r) * APITCH + kk * 32 + q * 8);
      bhalf8 b = *(const bhalf8*)(W2s + ((ct2 * 8 + kk) * 64 + lane) * 8);
      acc2 = __builtin_amdgcn_mfma_f32_16x16x32_bf16(a, b, acc2, 0, 0, 0);
    }
    int col = ct2 * 16 + r;
    if (rt == 0) {
      float b2v = LD<B16>(b2, col);
#pragma unroll
      for (int i = 0; i < 4; i++) {
        float dv = acc2[i] + b2v;
        int row = q * 4 + i;
        sm.outb[row * 33 + col] = dv;
        sm.sinb[row * 33 + col] = __sinf(dv);
        sm.cosb[row * 33 + col] = __cosf(dv);
      }
    } else {
#pragma unroll
      for (int i = 0; i < 4; i++)
        sm.outb[(rt * 16 + q * 4 + i) * 33 + col] = acc2[i];
    }
  }
  __syncthreads();

  // ---- Phase 5: coupling + physics + stores ----
  // sum_j B[b][j] sin(dv_b - dv_j) = sin(dv_b)*S_c - cos(dv_b)*S_s
  for (int slot = tid; slot < 512; slot += 256) {
    int s = slot >> 5, b = slot & 31;
    float dv  = sm.outb[s * 33 + b];
    float dt  = sm.outb[(16 + s) * 33 + b];
    float dtt = sm.outb[(32 + s) * 33 + b];
    float accC = 0.f, accS = 0.f;
#pragma unroll 8
    for (int j = 0; j < 32; j++) {
      float lb = sm.lambS[b * 34 + j];
      accC += lb * sm.cosb[s * 33 + j];
      accS += lb * sm.sinb[s * 33 + j];
    }
    float conn = sm.sinb[s * 33 + b] * accC - sm.cosb[s * 33 + b] * accS;
    int n = s0 + s;
    float phys = LD<B16>(lam_m, b) * LD<B16>(bwi, b) * dtt + LD<B16>(lam_d, b) * dt
               + conn - LD<B16>(powerP, n * 32 + b);
    ST<B16>(outP, n * 32 + b, dv);
    ST<B16>(outP, NPTS * 32 + n * 32 + b, dt);
    ST<B16>(outP, 2 * NPTS * 32 + n * 32 + b, phys);
  }
}

__global__ __launch_bounds__(256, 2)
void pinn_kernel(const void* timeP, const void* powerP,
                 const void* W0, const void* b0,
                 const void* b1, const void* b2,
                 const void* lam_m, const void* lam_d,
                 const void* lam_b, const void* bwi,
                 const void* W1_for_detect,
                 const ushort* __restrict__ W1s, const ushort* __restrict__ W2s,
                 void* outP) {
  __shared__ Smem sm;
  if (detect_bf16(W1_for_detect))
    pinn_body<true>(sm, timeP, powerP, W0, b0, b1, b2, lam_m, lam_d, lam_b, bwi,
                    W1s, W2s, outP);
  else
    pinn_body<false>(sm, timeP, powerP, W0, b0, b1, b2, lam_m, lam_d, lam_b, bwi,
                     W1s, W2s, outP);
}

extern "C" void kernel_launch(void* const* d_in, const int* in_sizes, int n_in,
                              void* d_out, int out_size, void* d_ws, size_t ws_size,
                              hipStream_t stream) {
  const void* timeP  = d_in[0];
  const void* powerP = d_in[1];
  const void* W0     = d_in[2];
  const void* b0     = d_in[3];
  const void* W1     = d_in[4];
  const void* b1     = d_in[5];
  const void* W2     = d_in[6];
  const void* b2     = d_in[7];
  const void* lam_m  = d_in[8];
  const void* lam_d  = d_in[9];
  const void* lam_b  = d_in[10];
  const void* bwi    = d_in[11];

  ushort* W1s = (ushort*)d_ws;            // 65536 elems = 128 KB
  ushort* W2s = W1s + H * H;              // 8192 elems  = 16 KB

  swz_kernel<<<288, 256, 0, stream>>>(W1, W2, W1s, W2s);
  pinn_kernel<<<NPTS / 16, 256, 0, stream>>>(timeP, powerP, W0, b0, b1, b2,
                                             lam_m, lam_d, lam_b, bwi, W1,
                                             W1s, W2s, d_out);
}

// Round 4
// 154.021 us; speedup vs baseline: 1.0391x; 1.0367x over previous
//
#include <hip/hip_runtime.h>

#define NPTS 65536
#define NB 32
#define H 256
#define TPB_TILES 8      // sample-tiles per block
#define GRID 512         // 512 * 8 * 16 = 65536 samples

typedef __attribute__((ext_vector_type(8))) short bhalf8;   // 8 bf16 in 4 VGPRs
typedef __attribute__((ext_vector_type(4))) float f32x4;

__device__ __forceinline__ float bf2f(ushort u) {
  union { unsigned u; float f; } x; x.u = ((unsigned)u) << 16; return x.f;
}
__device__ __forceinline__ ushort f2bf(float f) {
  union { float f; unsigned u; } x; x.f = f;
  unsigned r = x.u + 0x7FFFu + ((x.u >> 16) & 1u);
  return (ushort)(r >> 16);
}
__device__ __forceinline__ float fast_tanh(float z) {
  float e = __expf(2.0f * z);
  return 1.0f - 2.0f / (e + 1.0f);
}

// ---- runtime dtype detection from W1's bit pattern (wave-uniform) ----
__device__ __forceinline__ bool detect_bf16(const void* W1) {
  const ushort* u = (const ushort*)W1;
  int cnt = 0;
#pragma unroll
  for (int k = 0; k < 64; k++) {
    int e = (u[2 * k] >> 7) & 0xFF;
    cnt += (e >= 0x70 && e <= 0x7E) ? 1 : 0;
  }
  return cnt >= 32;
}

template<bool B16> __device__ __forceinline__ float LD(const void* p, int i) {
  if constexpr (B16) return bf2f(((const ushort*)p)[i]);
  else               return ((const float*)p)[i];
}
template<bool B16> __device__ __forceinline__ void ST(void* p, int i, float v) {
  if constexpr (B16) ((ushort*)p)[i] = f2bf(v);
  else               ((float*)p)[i] = v;
}

// Pre-swizzle W1 [256][256], W2 [256][32] into MFMA B-frag order (bf16):
// frag(ct,kk): lane l=q*16+r holds B[kk*32+q*8+j][ct*16+r], j=0..7.
__global__ void swz_kernel(const void* W1, const void* W2,
                           ushort* __restrict__ W1s, ushort* __restrict__ W2s) {
  int gid = blockIdx.x * 256 + threadIdx.x;
  bool b16 = detect_bf16(W1);
  if (gid < 65536) {
    int r = gid & 15, q = (gid >> 4) & 3, j = (gid >> 6) & 7;
    int kk = (gid >> 9) & 7, ct = gid >> 12;
    int src = (kk * 32 + q * 8 + j) * H + ct * 16 + r;
    int dst = ((ct * 8 + kk) * 64 + q * 16 + r) * 8 + j;
    float v = b16 ? bf2f(((const ushort*)W1)[src]) : ((const float*)W1)[src];
    W1s[dst] = f2bf(v);
  } else {
    int g2 = gid - 65536;                 // [0, 8192)
    int r = g2 & 15, q = (g2 >> 4) & 3, j = (g2 >> 6) & 7;
    int kk = (g2 >> 9) & 7, ct = (g2 >> 12) & 1;
    int src = (kk * 32 + q * 8 + j) * NB + ct * 16 + r;
    int dst = ((ct * 8 + kk) * 64 + q * 16 + r) * 8 + j;
    float v = b16 ? bf2f(((const ushort*)W2)[src]) : ((const float*)W2)[src];
    W2s[dst] = f2bf(v);
  }
}

#define APITCH 264   // bf16/row: 528B = 33*16B (b128-aligned rows)
#define SPITCH 36    // f32 pitch for lambS/sinb/cosb: 144B rows, 16B-aligned float4

struct Smem {
  alignas(16) ushort Abuf[48 * APITCH];    // 25344 B: A for GEMM1, then h1
  alignas(16) ushort W2lds[8192];          // 16384 B: W2 B-frags (block-resident)
  alignas(16) float outb[48 * 33];         //  6336 B
  alignas(16) float lambS[NB * SPITCH];    //  4608 B
  alignas(16) float sinb[16 * SPITCH];     //  2304 B
  alignas(16) float cosb[16 * SPITCH];     //  2304 B
  alignas(16) float w0c[H];                //  1024 B
  alignas(16) float b0c[H];                //  1024 B
};                                         // ~59.4 KB -> 2 blocks/CU

template<bool B16>
__device__ void pinn_body(Smem& sm,
                          const void* timeP, const void* powerP,
                          const void* W0, const void* b0,
                          const void* b1, const void* b2,
                          const void* lam_m, const void* lam_d,
                          const void* lam_b, const void* bwi,
                          const ushort* __restrict__ W1s, const ushort* __restrict__ W2s,
                          void* outP) {
  const int tid = threadIdx.x;
  const int wave = tid >> 6, lane = tid & 63;
  const int q = lane >> 4, r = lane & 15;

  // ================= per-block preamble (amortized over 8 tiles) =============
  // lambda_b -> LDS f32 (pitch 36)
  for (int idx = tid; idx < NB * NB; idx += 256)
    sm.lambS[(idx >> 5) * SPITCH + (idx & 31)] = LD<B16>(lam_b, idx);
  // W0/b0 -> LDS f32
  if (tid < H) {
    sm.w0c[tid] = LD<B16>(W0, tid);
    sm.b0c[tid] = LD<B16>(b0, tid);
  }
  // W2 frags -> LDS (straight copy, 16B chunks)
#pragma unroll
  for (int i = 0; i < 4; i++) {
    int c = tid + i * 256;                 // 1024 chunks of 8 shorts
    *(bhalf8*)(sm.W2lds + c * 8) = *(const bhalf8*)(W2s + c * 8);
  }
  // W1 B-frags -> REGISTERS (once per block; kills per-tile L2 latency)
  bhalf8 w1f[4][8];
#pragma unroll
  for (int ci = 0; ci < 4; ci++)
#pragma unroll
    for (int kk = 0; kk < 8; kk++) {
      int ct = wave * 4 + ci;
      w1f[ci][kk] = *(const bhalf8*)(W1s + (((ct * 8 + kk) * 64) + lane) * 8);
    }
  __syncthreads();

  // ================= tile loop =============
#pragma unroll 1
  for (int it = 0; it < TPB_TILES; it++) {
    const int s0 = (blockIdx.x * TPB_TILES + it) * 16;

    // ---- Phase 1: A = [h0 ; h0' ; h0''] ; thread = (sample sl, k-block kt) ----
    {
      int sl = tid & 15;        // coalesced time load, b128 A-writes
      int kt = tid >> 4;
      float t = LD<B16>(timeP, s0 + sl);
      float x = t * 0.1f - 1.0f;           // 2t/TMAX - 1, TMAX=20
#pragma unroll
      for (int half = 0; half < 2; half++) {
        int k0 = kt * 16 + half * 8;
        bhalf8 hv, hd, hdd;
#pragma unroll
        for (int c = 0; c < 8; c++) {
          float w0v = sm.w0c[k0 + c];
          float pre = x * w0v + sm.b0c[k0 + c];
          float v = fast_tanh(pre);
          float cc = w0v * 0.1f;
          float s2 = 1.0f - v * v;
          float d1 = s2 * cc;
          float d2 = -2.0f * v * d1 * cc;
          hv[c]  = (short)f2bf(v);
          hd[c]  = (short)f2bf(d1);
          hdd[c] = (short)f2bf(d2);
        }
        int off = sl * APITCH + k0;
        *(bhalf8*)(sm.Abuf + off)               = hv;
        *(bhalf8*)(sm.Abuf + 16 * APITCH + off) = hd;
        *(bhalf8*)(sm.Abuf + 32 * APITCH + off) = hdd;
      }
    }
    __syncthreads();

    // ---- Phase 2: GEMM1 z1[48][256] = A @ W1, B entirely in registers ----
    f32x4 acc[3][4];
#pragma unroll
    for (int rt = 0; rt < 3; rt++)
#pragma unroll
      for (int ci = 0; ci < 4; ci++) { f32x4 z = {0.f,0.f,0.f,0.f}; acc[rt][ci] = z; }

#pragma unroll
    for (int kk = 0; kk < 8; kk++) {
      bhalf8 a0 = *(const bhalf8*)(sm.Abuf + (0 * 16 + r) * APITCH + kk * 32 + q * 8);
      bhalf8 a1 = *(const bhalf8*)(sm.Abuf + (1 * 16 + r) * APITCH + kk * 32 + q * 8);
      bhalf8 a2 = *(const bhalf8*)(sm.Abuf + (2 * 16 + r) * APITCH + kk * 32 + q * 8);
#pragma unroll
      for (int ci = 0; ci < 4; ci++) {
        acc[0][ci] = __builtin_amdgcn_mfma_f32_16x16x32_bf16(a0, w1f[ci][kk], acc[0][ci], 0, 0, 0);
        acc[1][ci] = __builtin_amdgcn_mfma_f32_16x16x32_bf16(a1, w1f[ci][kk], acc[1][ci], 0, 0, 0);
        acc[2][ci] = __builtin_amdgcn_mfma_f32_16x16x32_bf16(a2, w1f[ci][kk], acc[2][ci], 0, 0, 0);
      }
    }
    __syncthreads();   // waves done reading Abuf before overwrite with h1

    // ---- Phase 3: bias + tanh chain (C layout: col=lane&15, row=q*4+i) ----
#pragma unroll
    for (int ci = 0; ci < 4; ci++) {
      int col = (wave * 4 + ci) * 16 + r;
      float b1v = LD<B16>(b1, col);
#pragma unroll
      for (int i = 0; i < 4; i++) {
        float zv  = acc[0][ci][i] + b1v;
        float zd  = acc[1][ci][i];
        float zdd = acc[2][ci][i];
        float hv  = fast_tanh(zv);
        float s2  = 1.0f - hv * hv;
        float hd  = s2 * zd;
        float hdd = s2 * zdd - 2.0f * hv * hd * zd;
        int s = q * 4 + i;
        sm.Abuf[s * APITCH + col]        = f2bf(hv);
        sm.Abuf[(16 + s) * APITCH + col] = f2bf(hd);
        sm.Abuf[(32 + s) * APITCH + col] = f2bf(hdd);
      }
    }
    __syncthreads();

    // ---- Phase 4: GEMM2 out[48][32] = h1 @ W2 (B from LDS); sin/cos on rt=0 ----
    for (int tI = wave; tI < 6; tI += 4) {
      int rt = tI >> 1, ct2 = tI & 1;
      f32x4 acc2 = {0.f,0.f,0.f,0.f};
#pragma unroll
      for (int kk = 0; kk < 8; kk++) {
        bhalf8 a = *(const bhalf8*)(sm.Abuf + (rt * 16 + r) * APITCH + kk * 32 + q * 8);
        bhalf8 b = *(const bhalf8*)(sm.W2lds + ((ct2 * 8 + kk) * 64 + lane) * 8);
        acc2 = __builtin_amdgcn_mfma_f32_16x16x32_bf16(a, b, acc2, 0, 0, 0);
      }
      int col = ct2 * 16 + r;
      if (rt == 0) {
        float b2v = LD<B16>(b2, col);
#pragma unroll
        for (int i = 0; i < 4; i++) {
          float dv = acc2[i] + b2v;
          int row = q * 4 + i;
          sm.outb[row * 33 + col] = dv;
          sm.sinb[row * SPITCH + col] = __sinf(dv);
          sm.cosb[row * SPITCH + col] = __cosf(dv);
        }
      } else {
#pragma unroll
        for (int i = 0; i < 4; i++)
          sm.outb[(rt * 16 + q * 4 + i) * 33 + col] = acc2[i];
      }
    }
    __syncthreads();

    // ---- Phase 5: coupling (float4-vectorized) + physics + stores ----
#pragma unroll
    for (int slot = tid; slot < 512; slot += 256) {
      int s = slot >> 5, b = slot & 31;
      float accC = 0.f, accS = 0.f;
#pragma unroll
      for (int j4 = 0; j4 < 32; j4 += 4) {
        float4 lb = *(const float4*)&sm.lambS[b * SPITCH + j4];
        float4 cb = *(const float4*)&sm.cosb[s * SPITCH + j4];
        float4 sb = *(const float4*)&sm.sinb[s * SPITCH + j4];
        accC += lb.x * cb.x + lb.y * cb.y + lb.z * cb.z + lb.w * cb.w;
        accS += lb.x * sb.x + lb.y * sb.y + lb.z * sb.z + lb.w * sb.w;
      }
      float dv  = sm.outb[s * 33 + b];
      float dt  = sm.outb[(16 + s) * 33 + b];
      float dtt = sm.outb[(32 + s) * 33 + b];
      float conn = sm.sinb[s * SPITCH + b] * accC - sm.cosb[s * SPITCH + b] * accS;
      int n = s0 + s;
      float phys = LD<B16>(lam_m, b) * LD<B16>(bwi, b) * dtt + LD<B16>(lam_d, b) * dt
                 + conn - LD<B16>(powerP, n * 32 + b);
      ST<B16>(outP, n * 32 + b, dv);
      ST<B16>(outP, NPTS * 32 + n * 32 + b, dt);
      ST<B16>(outP, 2 * NPTS * 32 + n * 32 + b, phys);
    }
    __syncthreads();   // outb/sinb/cosb consumed before next tile's Phase 4
  }
}

__global__ __launch_bounds__(256, 2)
void pinn_kernel(const void* timeP, const void* powerP,
                 const void* W0, const void* b0,
                 const void* b1, const void* b2,
                 const void* lam_m, const void* lam_d,
                 const void* lam_b, const void* bwi,
                 const void* W1_for_detect,
                 const ushort* __restrict__ W1s, const ushort* __restrict__ W2s,
                 void* outP) {
  __shared__ Smem sm;
  if (detect_bf16(W1_for_detect))
    pinn_body<true>(sm, timeP, powerP, W0, b0, b1, b2, lam_m, lam_d, lam_b, bwi,
                    W1s, W2s, outP);
  else
    pinn_body<false>(sm, timeP, powerP, W0, b0, b1, b2, lam_m, lam_d, lam_b, bwi,
                     W1s, W2s, outP);
}

extern "C" void kernel_launch(void* const* d_in, const int* in_sizes, int n_in,
                              void* d_out, int out_size, void* d_ws, size_t ws_size,
                              hipStream_t stream) {
  const void* timeP  = d_in[0];
  const void* powerP = d_in[1];
  const void* W0     = d_in[2];
  const void* b0     = d_in[3];
  const void* W1     = d_in[4];
  const void* b1     = d_in[5];
  const void* W2     = d_in[6];
  const void* b2     = d_in[7];
  const void* lam_m  = d_in[8];
  const void* lam_d  = d_in[9];
  const void* lam_b  = d_in[10];
  const void* bwi    = d_in[11];

  ushort* W1s = (ushort*)d_ws;            // 65536 elems = 128 KB
  ushort* W2s = W1s + H * H;              // 8192 elems  = 16 KB

  swz_kernel<<<288, 256, 0, stream>>>(W1, W2, W1s, W2s);
  pinn_kernel<<<GRID, 256, 0, stream>>>(timeP, powerP, W0, b0, b1, b2,
                                        lam_m, lam_d, lam_b, bwi, W1,
                                        W1s, W2s, d_out);
}

// Round 5
// 128.392 us; speedup vs baseline: 1.2465x; 1.1996x over previous
//
#include <hip/hip_runtime.h>

#define NPTS 65536
#define NB 32
#define H 256

typedef __attribute__((ext_vector_type(8))) short bhalf8;   // 8 bf16 = 4 VGPRs
typedef __attribute__((ext_vector_type(4))) float f32x4;

union BHU { bhalf8 h; uint u[4]; };

__device__ __forceinline__ float bf2f(ushort u) {
  union { uint x; float f; } c; c.x = ((uint)u) << 16; return c.f;
}
__device__ __forceinline__ ushort f2bf(float f) {            // RNE
  uint x = __float_as_uint(f);
  uint r = x + 0x7FFFu + ((x >> 16) & 1u);
  return (ushort)(r >> 16);
}
// pack two floats to bf16 pair, round-to-zero (1 ULP; inputs to MFMA only)
__device__ __forceinline__ uint packtr(float a, float b) {
  return (__float_as_uint(a) >> 16) | (__float_as_uint(b) & 0xFFFF0000u);
}
__device__ __forceinline__ float fast_tanh(float z) {
  float e = __expf(2.0f * z);
  return 1.0f - 2.0f / (e + 1.0f);
}

// dtype detect from W1 bit pattern: 32 even-halfword exponent samples (8 x uint4)
__device__ __forceinline__ bool detect_bf16(const void* W1) {
  const uint4* p = (const uint4*)W1;
  int cnt = 0;
#pragma unroll
  for (int i = 0; i < 8; i++) {
    uint4 v = p[i];
    uint d[4] = {v.x, v.y, v.z, v.w};
#pragma unroll
    for (int k = 0; k < 4; k++) {
      int e = (d[k] >> 7) & 0xFF;                 // exponent of low (even) halfword
      cnt += (e >= 0x70 && e <= 0x7E) ? 1 : 0;
    }
  }
  return cnt >= 16;
}

template<bool B16> __device__ __forceinline__ float LD(const void* p, int i) {
  if constexpr (B16) return bf2f(((const ushort*)p)[i]);
  else               return ((const float*)p)[i];
}
template<bool B16> __device__ __forceinline__ void ST(void* p, int i, float v) {
  if constexpr (B16) ((ushort*)p)[i] = f2bf(v);
  else               ((float*)p)[i] = v;
}

// Pre-swizzle W1 [256][256], W2 [256][32] into MFMA B-frag order (bf16):
// frag(ct,kk): lane l=q*16+r holds B[kk*32+q*8+j][ct*16+r], j=0..7.
__global__ void swz_kernel(const void* W1, const void* W2,
                           ushort* __restrict__ W1s, ushort* __restrict__ W2s) {
  int gid = blockIdx.x * 256 + threadIdx.x;
  bool b16 = detect_bf16(W1);
  if (gid < 65536) {
    int r = gid & 15, q = (gid >> 4) & 3, j = (gid >> 6) & 7;
    int kk = (gid >> 9) & 7, ct = gid >> 12;
    int src = (kk * 32 + q * 8 + j) * H + ct * 16 + r;
    int dst = ((ct * 8 + kk) * 64 + q * 16 + r) * 8 + j;
    float v = b16 ? bf2f(((const ushort*)W1)[src]) : ((const float*)W1)[src];
    W1s[dst] = f2bf(v);
  } else {
    int g2 = gid - 65536;
    int r = g2 & 15, q = (g2 >> 4) & 3, j = (g2 >> 6) & 7;
    int kk = (g2 >> 9) & 7, ct = (g2 >> 12) & 1;
    int src = (kk * 32 + q * 8 + j) * NB + ct * 16 + r;
    int dst = ((ct * 8 + kk) * 64 + q * 16 + r) * 8 + j;
    float v = b16 ? bf2f(((const ushort*)W2)[src]) : ((const float*)W2)[src];
    W2s[dst] = f2bf(v);
  }
}

#define PPITCH 36    // f32 cols of pair buffer (32 used): 144B rows, float4-aligned
#define SPITCH 40    // bf16 cols of sin/cos buffer: 80B rows, b128-aligned

struct Smem {
  alignas(16) float  pair[4][48 * PPITCH];   // 4 x 6912 B  wave-private h1 k-chunk
  alignas(16) ushort scb[4][2 * 16 * SPITCH];// 4 x 2560 B  wave-private sin/cos (bf16)
  alignas(16) ushort W2l[16 * 64 * 8];       // 16384 B     W2 B-frags
  alignas(16) ushort lamTf[2 * 64 * 8];      //  2048 B     lambda^T B-frags (bf16)
  alignas(16) float  w0c[H], b0c[H], b1c[H]; //  3072 B
  alignas(16) float  b2c[NB], lamMc[NB], lamDc[NB]; // 384 B
};                                           // ~59.8 KB -> 2 blocks/CU

template<bool B16>
__device__ void pinn_body(Smem& sm,
                          const void* timeP, const void* powerP,
                          const void* W0, const void* b0,
                          const void* b1, const void* b2,
                          const void* lam_m, const void* lam_d,
                          const void* lam_b, const void* bwi,
                          const ushort* __restrict__ W1s, void* outP) {
  const int tid = threadIdx.x;
  const int wave = tid >> 6, lane = tid & 63;
  const int q = lane >> 4, r = lane & 15;

  // ================= preamble (one barrier total) =================
  // W2 frags -> LDS (16 KB straight copy)
#pragma unroll
  for (int i = 0; i < 4; i++) {
    int c = tid + i * 256;
    *(bhalf8*)(sm.W2l + c * 8) = *(const bhalf8*)(((const ushort*)W1s) + H * H + c * 8);
  }
  // lambda^T B-frags: lane holds lam_b[ct*16+r][q*8+j]
  if (tid < 128) {
    int ct = tid >> 6, l2 = tid & 63, qq = l2 >> 4, rr = l2 & 15;
    BHU t;
#pragma unroll
    for (int j = 0; j < 8; j += 2)
      t.u[j >> 1] = packtr(LD<B16>(lam_b, (ct * 16 + rr) * NB + qq * 8 + j),
                           LD<B16>(lam_b, (ct * 16 + rr) * NB + qq * 8 + j + 1));
    *(bhalf8*)(sm.lamTf + tid * 8) = t.h;
  }
  if (tid < H) {
    sm.w0c[tid] = LD<B16>(W0, tid);
    sm.b0c[tid] = LD<B16>(b0, tid);
    sm.b1c[tid] = LD<B16>(b1, tid);
  }
  if (tid < NB) {
    sm.b2c[tid]   = LD<B16>(b2, tid);
    sm.lamMc[tid] = LD<B16>(lam_m, tid) * LD<B16>(bwi, tid);
    sm.lamDc[tid] = LD<B16>(lam_d, tid);
  }
  __syncthreads();

  // ================= wave-autonomous tile =================
  const int s0 = (blockIdx.x * 4 + wave) * 16;
  float* pb = &sm.pair[wave][0];
  ushort* sc = &sm.scb[wave][0];

  float t = LD<B16>(timeP, s0 + r);
  float x = t * 0.1f - 1.0f;               // 2t/TMAX - 1, TMAX = 20

  // ---- A-frags in registers: a{ch}f[kk], lane holds Ach[r][kk*32+q*8+j] ----
  bhalf8 a0f[8], a1f[8], a2f[8];
#pragma unroll
  for (int kk = 0; kk < 8; kk++) {
    int k0 = kk * 32 + q * 8;
    BHU t0, t1, t2;
    float vv[8], d1v[8], d2v[8];
#pragma unroll
    for (int j = 0; j < 8; j++) {
      float w0v = sm.w0c[k0 + j];
      float pre = x * w0v + sm.b0c[k0 + j];
      float v = fast_tanh(pre);
      float cc = w0v * 0.1f;
      float s2 = 1.0f - v * v;
      vv[j] = v; d1v[j] = s2 * cc; d2v[j] = -2.0f * v * d1v[j] * cc;
    }
#pragma unroll
    for (int j = 0; j < 8; j += 2) {
      t0.u[j >> 1] = packtr(vv[j], vv[j + 1]);
      t1.u[j >> 1] = packtr(d1v[j], d1v[j + 1]);
      t2.u[j >> 1] = packtr(d2v[j], d2v[j + 1]);
    }
    a0f[kk] = t0.h; a1f[kk] = t1.h; a2f[kk] = t2.h;
  }

  // ---- fused GEMM1 -> tanh chain -> GEMM2 over 16 col-tiles ----
  f32x4 acc2[3][2];
#pragma unroll
  for (int ch = 0; ch < 3; ch++)
#pragma unroll
    for (int c2 = 0; c2 < 2; c2++) { f32x4 z = {0.f,0.f,0.f,0.f}; acc2[ch][c2] = z; }

  bhalf8 bf[8];
#pragma unroll
  for (int kk = 0; kk < 8; kk++)
    bf[kk] = *(const bhalf8*)(W1s + ((0 * 8 + kk) * 64 + lane) * 8);

#pragma unroll 2
  for (int ct = 0; ct < 16; ct++) {
    // prefetch next ct's B-frags (L2-resident stream)
    bhalf8 bn[8];
    int ctn = (ct < 15) ? ct + 1 : 15;
#pragma unroll
    for (int kk = 0; kk < 8; kk++)
      bn[kk] = *(const bhalf8*)(W1s + ((ctn * 8 + kk) * 64 + lane) * 8);

    f32x4 c0 = {0.f,0.f,0.f,0.f}, c1 = c0, c2 = c0;
#pragma unroll
    for (int kk = 0; kk < 8; kk++) {
      c0 = __builtin_amdgcn_mfma_f32_16x16x32_bf16(a0f[kk], bf[kk], c0, 0, 0, 0);
      c1 = __builtin_amdgcn_mfma_f32_16x16x32_bf16(a1f[kk], bf[kk], c1, 0, 0, 0);
      c2 = __builtin_amdgcn_mfma_f32_16x16x32_bf16(a2f[kk], bf[kk], c2, 0, 0, 0);
    }
    // tanh chain on C-layout (col=r within tile, rows q*4+i) -> wave-private pair buf
    float b1v = sm.b1c[ct * 16 + r];
    int lc = (ct & 1) * 16 + r;
#pragma unroll
    for (int i = 0; i < 4; i++) {
      float hv  = fast_tanh(c0[i] + b1v);
      float s2  = 1.0f - hv * hv;
      float hd  = s2 * c1[i];
      float hdd = s2 * c2[i] - 2.0f * hv * hd * c1[i];
      int row = q * 4 + i;
      pb[row * PPITCH + lc]              = hv;
      pb[(16 + row) * PPITCH + lc]       = hd;
      pb[(32 + row) * PPITCH + lc]       = hdd;
    }
    if (ct & 1) {            // consume completed 32-col pair as GEMM2 k-chunk p
      int p = ct >> 1;
#pragma unroll
      for (int ch = 0; ch < 3; ch++) {
        const float4* rp = (const float4*)&pb[(ch * 16 + r) * PPITCH + q * 8];
        float4 u0 = rp[0], u1 = rp[1];
        BHU hf;
        hf.u[0] = packtr(u0.x, u0.y); hf.u[1] = packtr(u0.z, u0.w);
        hf.u[2] = packtr(u1.x, u1.y); hf.u[3] = packtr(u1.z, u1.w);
#pragma unroll
        for (int c2i = 0; c2i < 2; c2i++) {
          bhalf8 w2f = *(const bhalf8*)(sm.W2l + ((c2i * 8 + p) * 64 + lane) * 8);
          acc2[ch][c2i] = __builtin_amdgcn_mfma_f32_16x16x32_bf16(hf.h, w2f, acc2[ch][c2i], 0, 0, 0);
        }
      }
    }
#pragma unroll
    for (int kk = 0; kk < 8; kk++) bf[kk] = bn[kk];
  }

  // ---- epilogue: angles, sin/cos, coupling via MFMA, physics ----
  float dv[2][4], dt[2][4], dtt[2][4], sn[2][4], cs[2][4], Pv[2][4];
#pragma unroll
  for (int c2 = 0; c2 < 2; c2++) {
    int b = c2 * 16 + r;
    float b2v = sm.b2c[b];
#pragma unroll
    for (int i = 0; i < 4; i++) {
      int n = s0 + q * 4 + i;
      Pv[c2][i] = LD<B16>(powerP, n * NB + b);     // issue loads early
      dv[c2][i]  = acc2[0][c2][i] + b2v;
      dt[c2][i]  = acc2[1][c2][i];
      dtt[c2][i] = acc2[2][c2][i];
      sn[c2][i] = __sinf(dv[c2][i]);
      cs[c2][i] = __cosf(dv[c2][i]);
      sc[0 * 16 * SPITCH + (q * 4 + i) * SPITCH + b] = f2bf(sn[c2][i]);
      sc[1 * 16 * SPITCH + (q * 4 + i) * SPITCH + b] = f2bf(cs[c2][i]);
      ST<B16>(outP, n * NB + b, dv[c2][i]);
      ST<B16>(outP, NPTS * NB + n * NB + b, dt[c2][i]);
    }
  }
  // coupling sums via MFMA: C = cosM @ lam^T, S = sinM @ lam^T (16x32 @ 32x32)
  bhalf8 snA = *(const bhalf8*)(sc + 0 * 16 * SPITCH + r * SPITCH + q * 8);
  bhalf8 csA = *(const bhalf8*)(sc + 1 * 16 * SPITCH + r * SPITCH + q * 8);
  f32x4 accC[2], accS[2];
#pragma unroll
  for (int c2 = 0; c2 < 2; c2++) {
    bhalf8 lt = *(const bhalf8*)(sm.lamTf + (c2 * 64 + lane) * 8);
    f32x4 z = {0.f,0.f,0.f,0.f};
    accC[c2] = __builtin_amdgcn_mfma_f32_16x16x32_bf16(csA, lt, z, 0, 0, 0);
    accS[c2] = __builtin_amdgcn_mfma_f32_16x16x32_bf16(snA, lt, z, 0, 0, 0);
  }
#pragma unroll
  for (int c2 = 0; c2 < 2; c2++) {
    int b = c2 * 16 + r;
    float lm = sm.lamMc[b], ld = sm.lamDc[b];
#pragma unroll
    for (int i = 0; i < 4; i++) {
      float conn = sn[c2][i] * accC[c2][i] - cs[c2][i] * accS[c2][i];
      float phys = lm * dtt[c2][i] + ld * dt[c2][i] + conn - Pv[c2][i];
      int n = s0 + q * 4 + i;
      ST<B16>(outP, 2 * NPTS * NB + n * NB + b, phys);
    }
  }
}

__global__ __launch_bounds__(256, 2)
void pinn_kernel(const void* timeP, const void* powerP,
                 const void* W0, const void* b0,
                 const void* b1, const void* b2,
                 const void* lam_m, const void* lam_d,
                 const void* lam_b, const void* bwi,
                 const void* W1_for_detect,
                 const ushort* __restrict__ W1s, void* outP) {
  __shared__ Smem sm;
  if (detect_bf16(W1_for_detect))
    pinn_body<true>(sm, timeP, powerP, W0, b0, b1, b2, lam_m, lam_d, lam_b, bwi,
                    W1s, outP);
  else
    pinn_body<false>(sm, timeP, powerP, W0, b0, b1, b2, lam_m, lam_d, lam_b, bwi,
                     W1s, outP);
}

extern "C" void kernel_launch(void* const* d_in, const int* in_sizes, int n_in,
                              void* d_out, int out_size, void* d_ws, size_t ws_size,
                              hipStream_t stream) {
  const void* timeP  = d_in[0];
  const void* powerP = d_in[1];
  const void* W0     = d_in[2];
  const void* b0     = d_in[3];
  const void* W1     = d_in[4];
  const void* b1     = d_in[5];
  const void* W2     = d_in[6];
  const void* b2     = d_in[7];
  const void* lam_m  = d_in[8];
  const void* lam_d  = d_in[9];
  const void* lam_b  = d_in[10];
  const void* bwi    = d_in[11];

  ushort* W1s = (ushort*)d_ws;            // W1 frags: 128 KB; W2 frags follow at +65536
  ushort* W2s = W1s + H * H;

  swz_kernel<<<288, 256, 0, stream>>>(W1, W2, W1s, W2s);
  // pinn reads W2 frags via W1s + H*H (same workspace)
  pinn_kernel<<<1024, 256, 0, stream>>>(timeP, powerP, W0, b0, b1, b2,
                                        lam_m, lam_d, lam_b, bwi, W1,
                                        W1s, d_out);
  (void)W2s;
}